// Round 8
// baseline (357.584 us; speedup 1.0000x reference)
//
#include <hip/hip_runtime.h>
#include <cstdint>
#include <cstddef>

// Problem constants: B=64, N=1024, D=512, C=512, K=16, GAMMA=0.3, TEMP=0.07
#define INV_TEMP 14.285714285714285714f
#define GAMMA_ 0.3f

// Rows: 0..65535 = vpat (b*1024+n); 65536..65599 = cls; 65600..65663 = pad.
#define ROWS_PAD 65664

typedef short short8 __attribute__((ext_vector_type(8)));
typedef short short4v __attribute__((ext_vector_type(4)));
typedef float floatx4 __attribute__((ext_vector_type(4)));

#if __has_builtin(__builtin_amdgcn_fmed3f)
#define MED3(v, hi, lo) __builtin_amdgcn_fmed3f((v), (hi), (lo))
#else
#define MED3(v, hi, lo) fmaxf(fminf((v), (hi)), (lo))
#endif

__device__ __forceinline__ unsigned short f2bf(float x) {
  unsigned int u = __float_as_uint(x);
  u += 0x7FFFu + ((u >> 16) & 1u);  // round-to-nearest-even
  return (unsigned short)(u >> 16);
}
__device__ __forceinline__ float bf2f(unsigned short h) {
  return __uint_as_float(((unsigned int)h) << 16);
}

// Branchless sorted-descending top-16 insert: 15 med3 + 1 max, depth-1 ILP.
__device__ __forceinline__ void insert16(float (&top)[16], float v) {
#pragma unroll
  for (int j = 15; j >= 1; --j) top[j] = MED3(v, top[j - 1], top[j]);
  top[0] = fmaxf(top[0], v);
}

#define GL16(srcp, dstp)                                                        \
  __builtin_amdgcn_global_load_lds(                                             \
      (const __attribute__((address_space(1))) void*)(srcp),                    \
      (__attribute__((address_space(3))) void*)(dstp), 16, 0, 0)

// ---------------------------------------------------------------------------
// Prep (r0 verified): wave-per-row. wid<512: text row -> l2norm + RNE bf16
// hi/lo (B matrix). wid 512..639: Aext row (cls raw fp32 copy rows 0..63;
// zeros 64..127). A-row norms are derived inside the GEMM.
__global__ __launch_bounds__(256) void prep_kernel(
    const float* __restrict__ vcls, const float* __restrict__ text,
    unsigned short* __restrict__ Bh, unsigned short* __restrict__ Bl,
    float* __restrict__ Aext) {
  const int wid = blockIdx.x * 4 + (threadIdx.x >> 6);
  const int lane = threadIdx.x & 63;
  if (wid < 512) {
    const float* src = text + (size_t)wid * 512;
    const float4 v0 = ((const float4*)src)[lane];
    const float4 v1 = ((const float4*)src)[lane + 64];
    float ss = v0.x * v0.x + v0.y * v0.y + v0.z * v0.z + v0.w * v0.w +
               v1.x * v1.x + v1.y * v1.y + v1.z * v1.z + v1.w * v1.w;
#pragma unroll
    for (int off = 32; off; off >>= 1) ss += __shfl_xor(ss, off);
    const float scale = 1.0f / fmaxf(sqrtf(ss), 1e-12f);
    float a[8] = {v0.x * scale, v0.y * scale, v0.z * scale, v0.w * scale,
                  v1.x * scale, v1.y * scale, v1.z * scale, v1.w * scale};
    ushort4 h0, l0, h1, l1;
    h0.x = f2bf(a[0]); l0.x = f2bf(a[0] - bf2f(h0.x));
    h0.y = f2bf(a[1]); l0.y = f2bf(a[1] - bf2f(h0.y));
    h0.z = f2bf(a[2]); l0.z = f2bf(a[2] - bf2f(h0.z));
    h0.w = f2bf(a[3]); l0.w = f2bf(a[3] - bf2f(h0.w));
    h1.x = f2bf(a[4]); l1.x = f2bf(a[4] - bf2f(h1.x));
    h1.y = f2bf(a[5]); l1.y = f2bf(a[5] - bf2f(h1.y));
    h1.z = f2bf(a[6]); l1.z = f2bf(a[6] - bf2f(h1.z));
    h1.w = f2bf(a[7]); l1.w = f2bf(a[7] - bf2f(h1.w));
    ((ushort4*)(Bh + (size_t)wid * 512))[lane] = h0;
    ((ushort4*)(Bh + (size_t)wid * 512))[lane + 64] = h1;
    ((ushort4*)(Bl + (size_t)wid * 512))[lane] = l0;
    ((ushort4*)(Bl + (size_t)wid * 512))[lane + 64] = l1;
  } else {
    const int r = wid - 512;  // 0..127
    float4* dst = (float4*)(Aext + (size_t)r * 512);
    if (r < 64) {
      const float4* src = (const float4*)(vcls + (size_t)r * 512);
      dst[lane] = src[lane];
      dst[lane + 64] = src[lane + 64];
    } else {
      const float4 z = {0.f, 0.f, 0.f, 0.f};
      dst[lane] = z;
      dst[lane + 64] = z;
    }
  }
}

// ---------------------------------------------------------------------------
// Raw-A split-bf16 GEMM (r7 measured-best, unchanged): convert-once-in-LDS,
// 3 barriers/k-tile, norms via per-slot ssq + lane-group reduce + sInv table.
__global__ __launch_bounds__(256) void gemm_raw_kernel(
    const float* __restrict__ Apat, const float* __restrict__ Aext,
    const unsigned short* __restrict__ Bhi, const unsigned short* __restrict__ Blo,
    float* __restrict__ Cout, float* __restrict__ pstat) {
  __shared__ __align__(16) unsigned char smem[32768];
  unsigned short* sBh = (unsigned short*)(smem + 16384);
  unsigned short* sBl = (unsigned short*)(smem + 24576);
  const int tid = threadIdx.x;
  const int lane = tid & 63;
  const int w = tid >> 6;
  const int wm = w >> 1, wn = w & 1;

  const int L = blockIdx.x;  // 0..2051
  int bm, bn;
  if (L < 2048) {
    const int xcd = L & 7;
    const int slot = L >> 3;
    bn = slot & 3;
    bm = (slot >> 2) * 8 + xcd;
  } else {
    bm = 512;
    bn = L - 2048;
  }
  const float* Abase =
      (bm < 512) ? (Apat + (size_t)bm * 128 * 512) : Aext;

  unsigned aSrc[4];
#pragma unroll
  for (int q = 0; q < 4; ++q) {
    const int s = tid + q * 256;
    const int row = s >> 3, pos = s & 7;
    const int g = pos ^ (row & 7);
    aSrc[q] = (unsigned)row * 512u + (unsigned)g * 4u;  // float offset
  }
  const int m0 = tid >> 2, g0 = (tid & 3) ^ ((m0 >> 1) & 3);
  const int i1 = 256 + tid;
  const int m1 = i1 >> 2, g1 = (i1 & 3) ^ ((m1 >> 1) & 3);
  const unsigned bO0 = (unsigned)(bn * 128 + m0) * 512u + (unsigned)g0 * 8u;
  const unsigned bO1 = (unsigned)(bn * 128 + m1) * 512u + (unsigned)g1 * 8u;

  const int l15 = lane & 15, kg = lane >> 4;
  int fA0[4], fA1[4], cB[4];
#pragma unroll
  for (int i = 0; i < 4; ++i) {
    const int ml = wm * 64 + i * 16 + l15;
    const int p0 = (2 * kg) ^ (ml & 7);
    const int p1 = (2 * kg + 1) ^ (ml & 7);
    fA0[i] = (ml * 8 + p0) * 16;  // byte offset of slot
    fA1[i] = (ml * 8 + p1) * 16;
    const int nl = wn * 64 + i * 16 + l15;
    cB[i] = (nl * 4 + (kg ^ ((nl >> 1) & 3))) * 8;  // ushort index
  }

  floatx4 acc[4][4] = {};
  float ssqp[4] = {0.f, 0.f, 0.f, 0.f};

#pragma unroll 1
  for (int ks = 0; ks < 16; ++ks) {
    const unsigned ko = (unsigned)ks * 32u;
#pragma unroll
    for (int q = 0; q < 4; ++q)
      GL16(Abase + aSrc[q] + ko, (unsigned short*)smem + (w * 512 + q * 2048));
    GL16(Bhi + bO0 + ko, sBh + (unsigned)tid * 8u);
    GL16(Bhi + bO1 + ko, sBh + 2048u + (unsigned)tid * 8u);
    GL16(Blo + bO0 + ko, sBl + (unsigned)tid * 8u);
    GL16(Blo + bO1 + ko, sBl + 2048u + (unsigned)tid * 8u);
    __syncthreads();  // (a) tile staged

#pragma unroll
    for (int q = 0; q < 4; ++q) {
      const int s = tid + q * 256;
      const float4 x = *(const float4*)(smem + s * 16);
      const float xs[4] = {x.x, x.y, x.z, x.w};
      unsigned hp[4], lp[4];
#pragma unroll
      for (int e = 0; e < 4; ++e) {
        const float f = xs[e];
        ssqp[q] = fmaf(f, f, ssqp[q]);
        const unsigned u = __float_as_uint(f) + 0x8000u;  // round-half-away
        hp[e] = u >> 16;
        const float hif = __uint_as_float(u & 0xFFFF0000u);
        lp[e] = __float_as_uint(f - hif) >> 16;  // exact resid, trunc
      }
      uint4 o;
      o.x = hp[0] | (hp[1] << 16);
      o.y = hp[2] | (hp[3] << 16);
      o.z = lp[0] | (lp[1] << 16);
      o.w = lp[2] | (lp[3] << 16);
      *(uint4*)(smem + s * 16) = o;
    }
    __syncthreads();  // (b) converted tile visible

    short8 bh[4], bl[4];
#pragma unroll
    for (int j = 0; j < 4; ++j) {
      bh[j] = *(const short8*)(sBh + cB[j]);
      bl[j] = *(const short8*)(sBl + cB[j]);
    }
#pragma unroll
    for (int i = 0; i < 4; ++i) {
      const short4v h0 = *(const short4v*)(smem + fA0[i]);
      const short4v l0 = *(const short4v*)(smem + fA0[i] + 8);
      const short4v h1 = *(const short4v*)(smem + fA1[i]);
      const short4v l1 = *(const short4v*)(smem + fA1[i] + 8);
      short8 ah, al;
      ah[0] = h0[0]; ah[1] = h0[1]; ah[2] = h0[2]; ah[3] = h0[3];
      ah[4] = h1[0]; ah[5] = h1[1]; ah[6] = h1[2]; ah[7] = h1[3];
      al[0] = l0[0]; al[1] = l0[1]; al[2] = l0[2]; al[3] = l0[3];
      al[4] = l1[0]; al[5] = l1[1]; al[6] = l1[2]; al[7] = l1[3];
#pragma unroll
      for (int j = 0; j < 4; ++j) {
        acc[i][j] = __builtin_amdgcn_mfma_f32_16x16x32_bf16(ah, bh[j], acc[i][j], 0, 0, 0);
        acc[i][j] = __builtin_amdgcn_mfma_f32_16x16x32_bf16(ah, bl[j], acc[i][j], 0, 0, 0);
        acc[i][j] = __builtin_amdgcn_mfma_f32_16x16x32_bf16(al, bh[j], acc[i][j], 0, 0, 0);
      }
    }
    __syncthreads();  // (c) frag reads done; next stage may overwrite
  }

#pragma unroll
  for (int q = 0; q < 4; ++q) {
    float s = ssqp[q];
    s += __shfl_xor(s, 1);
    s += __shfl_xor(s, 2);
    s += __shfl_xor(s, 4);
    ssqp[q] = s;
  }
  float* sInv = (float*)(smem + 16384);  // aliases sBh (dead)
  if ((tid & 7) == 0) {
#pragma unroll
    for (int q = 0; q < 4; ++q)
      sInv[(tid >> 3) + q * 32] = 1.0f / fmaxf(sqrtf(ssqp[q]), 1e-12f);
  }
  __syncthreads();

  // C/D layout: col=lane&15, row=(lane>>4)*4+reg  [m89/m91 verified]
  const int quad = kg;
  const unsigned rowb0 = (unsigned)(bm * 128 + wm * 64 + quad * 4);
  const unsigned colb0 = (unsigned)(bn * 128 + wn * 64 + l15);
  const int pk = bn * 2 + wn;  // pstat slot 0..7
#pragma unroll
  for (int i = 0; i < 4; ++i) {
    float iv[4];
#pragma unroll
    for (int r = 0; r < 4; ++r)
      iv[r] = sInv[wm * 64 + i * 16 + quad * 4 + r];
    float sc[4][4];
#pragma unroll
    for (int j = 0; j < 4; ++j)
#pragma unroll
      for (int r = 0; r < 4; ++r) sc[j][r] = acc[i][j][r] * iv[r];
#pragma unroll
    for (int j = 0; j < 4; ++j) {
      const unsigned col = colb0 + j * 16;
#pragma unroll
      for (int r = 0; r < 4; ++r)
        Cout[(size_t)(rowb0 + i * 16 + r) * 512 + col] = sc[j][r];
    }
#pragma unroll
    for (int r = 0; r < 4; ++r) {
      float se = __expf((sc[0][r] - 1.0f) * INV_TEMP) +
                 __expf((sc[1][r] - 1.0f) * INV_TEMP) +
                 __expf((sc[2][r] - 1.0f) * INV_TEMP) +
                 __expf((sc[3][r] - 1.0f) * INV_TEMP);
      se += __shfl_xor(se, 1);
      se += __shfl_xor(se, 2);
      se += __shfl_xor(se, 4);
      se += __shfl_xor(se, 8);
      if (l15 == 0) pstat[(size_t)(rowb0 + i * 16 + r) * 8 + pk] = se;
    }
  }
}

// ---------------------------------------------------------------------------
// Fused top-k v2: high-TLP. Previous version: 512 blocks x 4 waves = 2
// waves/SIMD -- latency-bound (8-load batch ~900cy HBM latency vs ~500cy of
// work, duty ~30%). Now: block=(b, cg of 64 cols), 512 thr as 8 row-eighths
// x 64 cols -> 512 blocks x 8 waves = 4096 waves (4/SIMD), 16-deep load
// batches (2x outstanding). Thread scans 128 rows of its column in the
// s = l*invT + LW[n] domain; per-col 8-way LDS merge (sTop padded to 17 to
// break the stride-64B merge conflict); rq==0 finishes (sum-exp of top-16,
// fused aff_g) and writes out. Zero intermediate global traffic.
__global__ __launch_bounds__(512) void topk_fused_kernel(
    const float* __restrict__ L, const float* __restrict__ pstat,
    float* __restrict__ out) {
  const int b = blockIdx.x;    // 0..63
  const int cg = blockIdx.y;   // 0..7
  const int tid = threadIdx.x; // 0..511
  const int rq = tid >> 6;     // row-eighth 0..7
  const int cl = tid & 63;
  const int c = cg * 64 + cl;

  __shared__ float sLW[1024];        // 4 KB
  __shared__ float sTop[7][64][17];  // padded inner: 29.75 KB

  // Phase A: LW[n] = -(ln(sum_k pstat[n][k]) + invT) for all 1024 rows of b.
#pragma unroll
  for (int q = 0; q < 2; ++q) {
    const int r = tid * 2 + q;  // 0..1023
    const float* p = pstat + ((size_t)b * 1024 + r) * 8;
    float S = 0.f;
#pragma unroll
    for (int k = 0; k < 8; ++k) S += p[k];
    sLW[r] = -(__logf(S) + INV_TEMP);
  }
  __syncthreads();

  // Phase B: per-thread top-16 over its 128 rows (col c), 16 loads in flight.
  float top[16];
#pragma unroll
  for (int j = 0; j < 16; ++j) top[j] = -3.0e38f;
  const float* Lp = L + ((size_t)b * 1024 + (size_t)rq * 128) * 512 + c;
  const int lwb = rq * 128;
#pragma unroll 1
  for (int n0 = 0; n0 < 128; n0 += 16) {
    float v[16];
#pragma unroll
    for (int u = 0; u < 16; ++u) v[u] = Lp[(size_t)(n0 + u) * 512];
#pragma unroll
    for (int u = 0; u < 16; ++u)
      insert16(top, fmaf(v[u], INV_TEMP, sLW[lwb + n0 + u]));
  }

  // Phase C: merge 8 eighths per column; finish.
  if (rq > 0) {
#pragma unroll
    for (int j = 0; j < 16; ++j) sTop[rq - 1][cl][j] = top[j];
  }
  __syncthreads();
  if (rq == 0) {
#pragma unroll
    for (int kb = 0; kb < 7; ++kb) {
      float v[16];
#pragma unroll
      for (int j = 0; j < 16; ++j) v[j] = sTop[kb][cl][j];
#pragma unroll
      for (int j = 0; j < 16; ++j) insert16(top, v[j]);
    }
    float se = 0.f;
#pragma unroll
    for (int j = 0; j < 16; ++j) se += __expf(top[j]);
    const float* pc = pstat + ((size_t)65536 + b) * 8;
    float S = 0.f;
#pragma unroll
    for (int k = 0; k < 8; ++k) S += pc[k];
    const float lg = L[((size_t)65536 + b) * 512 + c];
    const float ag = __expf(fmaf(lg, INV_TEMP, -(__logf(S) + INV_TEMP)));
    out[b * 512 + c] = GAMMA_ * ag + (1.0f - GAMMA_) * (se * (1.0f / 16.0f));
  }
}

// ---------------------------------------------------------------------------
extern "C" void kernel_launch(void* const* d_in, const int* in_sizes, int n_in,
                              void* d_out, int out_size, void* d_ws, size_t ws_size,
                              hipStream_t stream) {
  const float* vcls = (const float*)d_in[0];  // [64,512]
  const float* vpat = (const float*)d_in[1];  // [64,1024,512]
  const float* text = (const float*)d_in[2];  // [512,512]
  float* out = (float*)d_out;                 // [64,512]

  char* p = (char*)d_ws;
  auto carve = [&](size_t bytes) -> char* {
    char* r = p;
    p += (bytes + 255) & ~(size_t)255;
    return r;
  };
  // Minimal-footprint pipeline (~138 MB): raw-A gemm, no packed-A buffers.
  float* logits = (float*)carve((size_t)ROWS_PAD * 512 * 4);
  unsigned short* Bh = (unsigned short*)carve((size_t)512 * 512 * 2);
  unsigned short* Bl = (unsigned short*)carve((size_t)512 * 512 * 2);
  float* pstat = (float*)carve((size_t)ROWS_PAD * 8 * 4);
  float* Aext = (float*)carve((size_t)128 * 512 * 4);
  if ((size_t)(p - (char*)d_ws) > ws_size) return;

  prep_kernel<<<160, 256, 0, stream>>>(vcls, text, Bh, Bl, Aext);
  gemm_raw_kernel<<<2052, 256, 0, stream>>>(vpat, Aext, Bh, Bl, logits, pstat);
  topk_fused_kernel<<<dim3(64, 8), 512, 0, stream>>>(logits, pstat, out);
}

// Round 9
// 331.309 us; speedup vs baseline: 1.0793x; 1.0793x over previous
//
#include <hip/hip_runtime.h>
#include <cstdint>
#include <cstddef>

// Problem constants: B=64, N=1024, D=512, C=512, K=16, GAMMA=0.3, TEMP=0.07
#define INV_TEMP 14.285714285714285714f
#define GAMMA_ 0.3f

// Rows: 0..65535 = vpat (b*1024+n); 65536..65599 = cls; 65600..65663 = pad.
#define ROWS_PAD 65664

typedef short short8 __attribute__((ext_vector_type(8)));
typedef float floatx4 __attribute__((ext_vector_type(4)));

#if __has_builtin(__builtin_amdgcn_fmed3f)
#define MED3(v, hi, lo) __builtin_amdgcn_fmed3f((v), (hi), (lo))
#else
#define MED3(v, hi, lo) fmaxf(fminf((v), (hi)), (lo))
#endif

__device__ __forceinline__ unsigned short f2bf(float x) {
  unsigned int u = __float_as_uint(x);
  u += 0x7FFFu + ((u >> 16) & 1u);  // round-to-nearest-even
  return (unsigned short)(u >> 16);
}
__device__ __forceinline__ float bf2f(unsigned short h) {
  return __uint_as_float(((unsigned int)h) << 16);
}

// Branchless sorted-descending top-16 insert: 15 med3 + 1 max, depth-1 ILP.
__device__ __forceinline__ void insert16(float (&top)[16], float v) {
#pragma unroll
  for (int j = 15; j >= 1; --j) top[j] = MED3(v, top[j - 1], top[j]);
  top[0] = fmaxf(top[0], v);
}

#define GL16(srcp, dstp)                                                        \
  __builtin_amdgcn_global_load_lds(                                             \
      (const __attribute__((address_space(1))) void*)(srcp),                    \
      (__attribute__((address_space(3))) void*)(dstp), 16, 0, 0)

// ---------------------------------------------------------------------------
// Prep (r0 verified): wave-per-row. wid<512: text row -> l2norm + RNE bf16
// hi/lo (B matrix). wid 512..639: Aext row (cls raw fp32 copy rows 0..63;
// zeros 64..127). A-row norms are derived inside the GEMM.
__global__ __launch_bounds__(256) void prep_kernel(
    const float* __restrict__ vcls, const float* __restrict__ text,
    unsigned short* __restrict__ Bh, unsigned short* __restrict__ Bl,
    float* __restrict__ Aext) {
  const int wid = blockIdx.x * 4 + (threadIdx.x >> 6);
  const int lane = threadIdx.x & 63;
  if (wid < 512) {
    const float* src = text + (size_t)wid * 512;
    const float4 v0 = ((const float4*)src)[lane];
    const float4 v1 = ((const float4*)src)[lane + 64];
    float ss = v0.x * v0.x + v0.y * v0.y + v0.z * v0.z + v0.w * v0.w +
               v1.x * v1.x + v1.y * v1.y + v1.z * v1.z + v1.w * v1.w;
#pragma unroll
    for (int off = 32; off; off >>= 1) ss += __shfl_xor(ss, off);
    const float scale = 1.0f / fmaxf(sqrtf(ss), 1e-12f);
    float a[8] = {v0.x * scale, v0.y * scale, v0.z * scale, v0.w * scale,
                  v1.x * scale, v1.y * scale, v1.z * scale, v1.w * scale};
    ushort4 h0, l0, h1, l1;
    h0.x = f2bf(a[0]); l0.x = f2bf(a[0] - bf2f(h0.x));
    h0.y = f2bf(a[1]); l0.y = f2bf(a[1] - bf2f(h0.y));
    h0.z = f2bf(a[2]); l0.z = f2bf(a[2] - bf2f(h0.z));
    h0.w = f2bf(a[3]); l0.w = f2bf(a[3] - bf2f(h0.w));
    h1.x = f2bf(a[4]); l1.x = f2bf(a[4] - bf2f(h1.x));
    h1.y = f2bf(a[5]); l1.y = f2bf(a[5] - bf2f(h1.y));
    h1.z = f2bf(a[6]); l1.z = f2bf(a[6] - bf2f(h1.z));
    h1.w = f2bf(a[7]); l1.w = f2bf(a[7] - bf2f(h1.w));
    ((ushort4*)(Bh + (size_t)wid * 512))[lane] = h0;
    ((ushort4*)(Bh + (size_t)wid * 512))[lane + 64] = h1;
    ((ushort4*)(Bl + (size_t)wid * 512))[lane] = l0;
    ((ushort4*)(Bl + (size_t)wid * 512))[lane + 64] = l1;
  } else {
    const int r = wid - 512;  // 0..127
    float4* dst = (float4*)(Aext + (size_t)r * 512);
    if (r < 64) {
      const float4* src = (const float4*)(vcls + (size_t)r * 512);
      dst[lane] = src[lane];
      dst[lane + 64] = src[lane + 64];
    } else {
      const float4 z = {0.f, 0.f, 0.f, 0.f};
      dst[lane] = z;
      dst[lane + 64] = z;
    }
  }
}

// ---------------------------------------------------------------------------
// Raw-A GEMM v3: lean skeleton + reg-convert staging.
// r7 (convert-in-LDS, BK=32, 3 barriers/step, 48 thin segments) ran 214us --
// the convert phase (~512cy, all waves) was serialized between barriers while
// the MFMA phase was only ~240cy. The lean kernel (same MFMA count, bf16
// inputs) ran 135us with stage->barrier->MFMA fat segments. This version
// keeps raw fp32 A (no pack kernel) but: BK=64; A converted in VGPRs during
// staging (global->reg->convert->ds_write into sAh|sAl); B via global_load_lds
// (lean's verified swizzle); ONE barrier then a 96-MFMA phase (3 terms x
// 2 k2 x 4i x 4j) reading lean's conflict-free b128 fragment layout; second
// barrier closes the tile. 8 tiles x 2 barriers = 16 (vs 48). Convert
// overlaps the in-flight B loads and the other resident block's MFMA.
// ssq rides conversion (slot partials; 16-lane-group reduce -> sInv table).
__global__ __launch_bounds__(256) void gemm_raw_kernel(
    const float* __restrict__ Apat, const float* __restrict__ Aext,
    const unsigned short* __restrict__ Bhi, const unsigned short* __restrict__ Blo,
    float* __restrict__ Cout, float* __restrict__ pstat) {
  __shared__ __align__(16) unsigned short smem[32768];  // 64 KB
  unsigned short* sAh = smem;          // [128][64] bf16 hi, chunk-swizzled
  unsigned short* sAl = smem + 8192;   // [128][64] bf16 lo
  unsigned short* sBh = smem + 16384;  // [128][64] bf16 hi
  unsigned short* sBl = smem + 24576;  // [128][64] bf16 lo
  const int tid = threadIdx.x;
  const int lane = tid & 63;
  const int w = tid >> 6;
  const int wm = w >> 1, wn = w & 1;

  const int L = blockIdx.x;  // 0..2051
  int bm, bn;
  if (L < 2048) {
    const int xcd = L & 7;
    const int slot = L >> 3;
    bn = slot & 3;
    bm = (slot >> 2) * 8 + xcd;
  } else {
    bm = 512;
    bn = L - 2048;
  }
  const float* Abase =
      (bm < 512) ? (Apat + (size_t)bm * 128 * 512) : Aext;

  // A staging: 2048 fp32 16B-slots (128 rows x 16); thread owns q*256+tid.
  // slot s: row = s>>4 (consec 16 lanes share a row -> 256B contiguous reads),
  // pos = s&15 (4 floats). LDS dest: K-chunk c = pos>>1, half = pos&1,
  // swizzled p = c ^ (row&7) -> ushort off row*64 + p*8 + half*4 (b64 write).
  unsigned aSrcOff[8], aDst[8], aRowq[8];
#pragma unroll
  for (int q = 0; q < 8; ++q) {
    const int s = q * 256 + tid;
    const unsigned row = (unsigned)(s >> 4);
    const unsigned pos = (unsigned)(s & 15);
    aRowq[q] = row;
    aSrcOff[q] = row * 512u + pos * 4u;  // float offset (+ko per tile)
    aDst[q] = row * 64u + (((pos >> 1) ^ (row & 7u)) * 8u) + (pos & 1u) * 4u;
  }
  // B staging (lean verified): 1024 slots; thread owns tid + q*256.
  unsigned bOff[4];
#pragma unroll
  for (int q = 0; q < 4; ++q) {
    const int s = tid + q * 256;
    const int row = s >> 3, pos = s & 7;
    const int g = pos ^ (row & 7);
    bOff[q] = (unsigned)(bn * 128 + row) * 512u + (unsigned)g * 8u;  // ushort
  }

  const int l15 = lane & 15, kg = lane >> 4;
  // Fragment LDS offsets (lean verified, 0 conflicts): k-step k2 chunk
  // c = k2*4+kg, swizzled p = c ^ (row&7).
  int fA[4][2], fB[4][2];
#pragma unroll
  for (int i = 0; i < 4; ++i) {
    const int ml = wm * 64 + i * 16 + l15;
    const int nl = wn * 64 + i * 16 + l15;
#pragma unroll
    for (int k2 = 0; k2 < 2; ++k2) {
      const int c = k2 * 4 + kg;
      fA[i][k2] = ml * 64 + (c ^ (ml & 7)) * 8;
      fB[i][k2] = nl * 64 + (c ^ (nl & 7)) * 8;
    }
  }

  floatx4 acc[4][4] = {};
  float ssqp[8] = {};  // per owned slot (row aRowq[q]) partials

#pragma unroll 1
  for (int t = 0; t < 8; ++t) {
    const unsigned ko = (unsigned)t * 64u;
    // Issue B tile loads (async, drain at the barrier).
#pragma unroll
    for (int q = 0; q < 4; ++q)
      GL16(Bhi + bOff[q] + ko, sBh + (w * 512 + q * 2048));
#pragma unroll
    for (int q = 0; q < 4; ++q)
      GL16(Blo + bOff[q] + ko, sBl + (w * 512 + q * 2048));
    // A: global->reg (8x float4, 256B contiguous per 16 lanes).
    float4 av[8];
#pragma unroll
    for (int q = 0; q < 8; ++q)
      av[q] = *(const float4*)(Abase + aSrcOff[q] + ko);
    // Convert in regs (overlaps B loads in flight), ds_write hi/lo.
#pragma unroll
    for (int q = 0; q < 8; ++q) {
      const float xs[4] = {av[q].x, av[q].y, av[q].z, av[q].w};
      unsigned hp[4], lp[4];
#pragma unroll
      for (int e = 0; e < 4; ++e) {
        const float f = xs[e];
        ssqp[q] = fmaf(f, f, ssqp[q]);
        const unsigned u = __float_as_uint(f) + 0x8000u;  // round-half-away
        hp[e] = u >> 16;
        const float hif = __uint_as_float(u & 0xFFFF0000u);
        lp[e] = __float_as_uint(f - hif) >> 16;  // exact resid, trunc
      }
      uint2 ho, lo;
      ho.x = hp[0] | (hp[1] << 16);
      ho.y = hp[2] | (hp[3] << 16);
      lo.x = lp[0] | (lp[1] << 16);
      lo.y = lp[2] | (lp[3] << 16);
      *(uint2*)(sAh + aDst[q]) = ho;
      *(uint2*)(sAl + aDst[q]) = lo;
    }
    __syncthreads();  // drains B gload_lds (vmcnt) + A ds_writes (lgkm)

    // Fat MFMA phase: 96 MFMA (3 split terms), lean fragment reads.
#pragma unroll
    for (int k2 = 0; k2 < 2; ++k2) {
      short8 ah[4], al[4], bh[4], bl[4];
#pragma unroll
      for (int i = 0; i < 4; ++i) {
        ah[i] = *(const short8*)(sAh + fA[i][k2]);
        al[i] = *(const short8*)(sAl + fA[i][k2]);
      }
#pragma unroll
      for (int j = 0; j < 4; ++j) {
        bh[j] = *(const short8*)(sBh + fB[j][k2]);
        bl[j] = *(const short8*)(sBl + fB[j][k2]);
      }
#pragma unroll
      for (int i = 0; i < 4; ++i)
#pragma unroll
        for (int j = 0; j < 4; ++j) {
          acc[i][j] = __builtin_amdgcn_mfma_f32_16x16x32_bf16(ah[i], bh[j], acc[i][j], 0, 0, 0);
          acc[i][j] = __builtin_amdgcn_mfma_f32_16x16x32_bf16(ah[i], bl[j], acc[i][j], 0, 0, 0);
          acc[i][j] = __builtin_amdgcn_mfma_f32_16x16x32_bf16(al[i], bh[j], acc[i][j], 0, 0, 0);
        }
    }
    __syncthreads();  // frag reads done; next tile may overwrite
  }

  // Row inverse norms. Slot q's row is shared by the 16-lane group
  // (lane&~15 .. +15): shfl_xor 1,2,4,8 sums the 16 slot partials.
  float* sInv = (float*)sBh;  // sBh dead after final barrier above
#pragma unroll
  for (int q = 0; q < 8; ++q) {
    float s = ssqp[q];
    s += __shfl_xor(s, 1);
    s += __shfl_xor(s, 2);
    s += __shfl_xor(s, 4);
    s += __shfl_xor(s, 8);
    if (l15 == 0) sInv[aRowq[q]] = 1.0f / fmaxf(sqrtf(s), 1e-12f);
  }
  __syncthreads();

  // C/D layout: col=lane&15, row=(lane>>4)*4+reg  [m89/m91 verified]
  const int quad = kg;
  const unsigned rowb0 = (unsigned)(bm * 128 + wm * 64 + quad * 4);
  const unsigned colb0 = (unsigned)(bn * 128 + wn * 64 + l15);
  const int pk = bn * 2 + wn;  // pstat slot 0..7
#pragma unroll
  for (int i = 0; i < 4; ++i) {
    float iv[4];
#pragma unroll
    for (int r = 0; r < 4; ++r)
      iv[r] = sInv[wm * 64 + i * 16 + quad * 4 + r];
    float sc[4][4];
#pragma unroll
    for (int j = 0; j < 4; ++j)
#pragma unroll
      for (int r = 0; r < 4; ++r) sc[j][r] = acc[i][j][r] * iv[r];
#pragma unroll
    for (int j = 0; j < 4; ++j) {
      const unsigned col = colb0 + j * 16;
#pragma unroll
      for (int r = 0; r < 4; ++r)
        Cout[(size_t)(rowb0 + i * 16 + r) * 512 + col] = sc[j][r];
    }
    // Fused partial sumexp (fixed max 1.0), reduce over l15 bits (cols).
#pragma unroll
    for (int r = 0; r < 4; ++r) {
      float se = __expf((sc[0][r] - 1.0f) * INV_TEMP) +
                 __expf((sc[1][r] - 1.0f) * INV_TEMP) +
                 __expf((sc[2][r] - 1.0f) * INV_TEMP) +
                 __expf((sc[3][r] - 1.0f) * INV_TEMP);
      se += __shfl_xor(se, 1);
      se += __shfl_xor(se, 2);
      se += __shfl_xor(se, 4);
      se += __shfl_xor(se, 8);
      if (l15 == 0) pstat[(size_t)(rowb0 + i * 16 + r) * 8 + pk] = se;
    }
  }
}

// ---------------------------------------------------------------------------
// Fused top-k (r8): block=(b, cg of 64 cols), 512 thr as 8 row-eighths x 64
// cols (4096 waves); 16-deep load batches; s = l*invT + LW[n]; 8-way LDS
// merge (sTop padded); rq==0 finishes (sum-exp + fused aff_g) and writes out.
__global__ __launch_bounds__(512) void topk_fused_kernel(
    const float* __restrict__ L, const float* __restrict__ pstat,
    float* __restrict__ out) {
  const int b = blockIdx.x;    // 0..63
  const int cg = blockIdx.y;   // 0..7
  const int tid = threadIdx.x; // 0..511
  const int rq = tid >> 6;     // row-eighth 0..7
  const int cl = tid & 63;
  const int c = cg * 64 + cl;

  __shared__ float sLW[1024];
  __shared__ float sTop[7][64][17];

#pragma unroll
  for (int q = 0; q < 2; ++q) {
    const int r = tid * 2 + q;  // 0..1023
    const float* p = pstat + ((size_t)b * 1024 + r) * 8;
    float S = 0.f;
#pragma unroll
    for (int k = 0; k < 8; ++k) S += p[k];
    sLW[r] = -(__logf(S) + INV_TEMP);
  }
  __syncthreads();

  float top[16];
#pragma unroll
  for (int j = 0; j < 16; ++j) top[j] = -3.0e38f;
  const float* Lp = L + ((size_t)b * 1024 + (size_t)rq * 128) * 512 + c;
  const int lwb = rq * 128;
#pragma unroll 1
  for (int n0 = 0; n0 < 128; n0 += 16) {
    float v[16];
#pragma unroll
    for (int u = 0; u < 16; ++u) v[u] = Lp[(size_t)(n0 + u) * 512];
#pragma unroll
    for (int u = 0; u < 16; ++u)
      insert16(top, fmaf(v[u], INV_TEMP, sLW[lwb + n0 + u]));
  }

  if (rq > 0) {
#pragma unroll
    for (int j = 0; j < 16; ++j) sTop[rq - 1][cl][j] = top[j];
  }
  __syncthreads();
  if (rq == 0) {
#pragma unroll
    for (int kb = 0; kb < 7; ++kb) {
      float v[16];
#pragma unroll
      for (int j = 0; j < 16; ++j) v[j] = sTop[kb][cl][j];
#pragma unroll
      for (int j = 0; j < 16; ++j) insert16(top, v[j]);
    }
    float se = 0.f;
#pragma unroll
    for (int j = 0; j < 16; ++j) se += __expf(top[j]);
    const float* pc = pstat + ((size_t)65536 + b) * 8;
    float S = 0.f;
#pragma unroll
    for (int k = 0; k < 8; ++k) S += pc[k];
    const float lg = L[((size_t)65536 + b) * 512 + c];
    const float ag = __expf(fmaf(lg, INV_TEMP, -(__logf(S) + INV_TEMP)));
    out[b * 512 + c] = GAMMA_ * ag + (1.0f - GAMMA_) * (se * (1.0f / 16.0f));
  }
}

// ---------------------------------------------------------------------------
extern "C" void kernel_launch(void* const* d_in, const int* in_sizes, int n_in,
                              void* d_out, int out_size, void* d_ws, size_t ws_size,
                              hipStream_t stream) {
  const float* vcls = (const float*)d_in[0];  // [64,512]
  const float* vpat = (const float*)d_in[1];  // [64,1024,512]
  const float* text = (const float*)d_in[2];  // [512,512]
  float* out = (float*)d_out;                 // [64,512]

  char* p = (char*)d_ws;
  auto carve = [&](size_t bytes) -> char* {
    char* r = p;
    p += (bytes + 255) & ~(size_t)255;
    return r;
  };
  // Minimal-footprint pipeline (~138 MB): raw-A gemm, no packed-A buffers.
  float* logits = (float*)carve((size_t)ROWS_PAD * 512 * 4);
  unsigned short* Bh = (unsigned short*)carve((size_t)512 * 512 * 2);
  unsigned short* Bl = (unsigned short*)carve((size_t)512 * 512 * 2);
  float* pstat = (float*)carve((size_t)ROWS_PAD * 8 * 4);
  float* Aext = (float*)carve((size_t)128 * 512 * 4);
  if ((size_t)(p - (char*)d_ws) > ws_size) return;

  prep_kernel<<<160, 256, 0, stream>>>(vcls, text, Bh, Bl, Aext);
  gemm_raw_kernel<<<2052, 256, 0, stream>>>(vpat, Aext, Bh, Bl, logits, pstat);
  topk_fused_kernel<<<dim3(64, 8), 512, 0, stream>>>(logits, pstat, out);
}